// Round 19
// baseline (122.862 us; speedup 1.0000x reference)
//
#include <hip/hip_runtime.h>
#include <math.h>

#define NEGF  (-1e30f)
#define BIGF  (1000000.0f)
#define SCALE_ (0.08838834764831845f)   // 1/sqrt(128)
#define L2INV_ (0.20762050593046014f)   // log2(10000)/64
#define QT 4

typedef __attribute__((ext_vector_type(4))) float f32x4;
typedef __attribute__((ext_vector_type(8))) short short8;
typedef __attribute__((ext_vector_type(4))) short short4v;
typedef __attribute__((ext_vector_type(8))) _Float16 half8;

#define GLDS16(gp, lp) __builtin_amdgcn_global_load_lds( \
    (const __attribute__((address_space(1))) void*)(gp), \
    (__attribute__((address_space(3))) void*)(lp), 16, 0, 0)

__device__ __forceinline__ short bf16_of(float f) {
    union { float f; unsigned u; } x; x.f = f;
    unsigned r = x.u + 0x7fffu + ((x.u >> 16) & 1u);
    return (short)(r >> 16);
}
__device__ __forceinline__ float f32_of_bf16bits(unsigned u16) {
    union { unsigned u; float f; } x; x.u = u16 << 16;
    return x.f;
}
__device__ __forceinline__ short f16_of(float f) {
    _Float16 h = (_Float16)f;
    union { _Float16 h; short s; } u; u.h = h;
    return u.s;
}
__device__ __forceinline__ float f32_of_f16(short s) {
    union { _Float16 h; short s; } u; u.s = s;
    return (float)u.h;
}

// -------- Kernel 0: fused xconv + wconv ------------------------------------
__global__ __launch_bounds__(256) void prep_kernel(
    const float* __restrict__ x, const float* __restrict__ Wq,
    const float* __restrict__ Wk, const float* __restrict__ Wv,
    const float* __restrict__ Wg, short* __restrict__ xhi,
    short* __restrict__ xlo, short* __restrict__ wthi, short* __restrict__ wtlo)
{
    const int bid = blockIdx.x;
    if (bid < 2048) {
        const int i = bid * 1024 + threadIdx.x * 4;
        float4 f = *(const float4*)(x + i);
        short4v hi, lo;
        float fv[4] = {f.x, f.y, f.z, f.w};
        #pragma unroll
        for (int c = 0; c < 4; ++c) {
            short h = f16_of(fv[c]);
            hi[c] = h;
            lo[c] = f16_of(fv[c] - f32_of_f16(h));
        }
        *(short4v*)(xhi + i) = hi;
        *(short4v*)(xlo + i) = lo;
    } else {
        __shared__ float tile[32][33];
        const int b2 = bid - 2048;
        const int ct = b2 % 50, kt = b2 / 50;
        const int c = threadIdx.x & 31, r0 = threadIdx.x >> 5;
        #pragma unroll
        for (int rr = 0; rr < 32; rr += 8) {
            int k = kt * 32 + r0 + rr;
            int gc = ct * 32 + c;
            float val;
            if (gc < 1024)      val = Wq[k * 1024 + gc];
            else if (gc < 1280) val = Wk[k * 256 + gc - 1024];
            else if (gc < 1536) val = Wv[k * 256 + gc - 1280];
            else if (gc < 1560) val = Wg[k * 24 + gc - 1536];
            else                val = 0.f;
            tile[r0 + rr][c] = val;
        }
        __syncthreads();
        #pragma unroll
        for (int rr = 0; rr < 32; rr += 8) {
            int col = ct * 32 + r0 + rr;
            int k = kt * 32 + c;
            float val = tile[c][r0 + rr];
            short hi = f16_of(val);
            short lo = f16_of(val - f32_of_f16(hi));
            wthi[(size_t)col * 1024 + k] = hi;
            wtlo[(size_t)col * 1024 + k] = lo;
        }
    }
}

// -------- Kernel 1: projections, split-fp16 MFMA, 64x64 tile ---------------
// grid (25, 32) = 800 blocks, 256 threads (4 waves of one 32x32 subtile).
// LDS 32KB -> ~5 blocks/CU: balanced residency (vs 400-block 2:1 imbalance).
__global__ __launch_bounds__(256) void proj_mfma_kernel(
    const short* __restrict__ xhi, const short* __restrict__ xlo,
    const short* __restrict__ wthi, const short* __restrict__ wtlo,
    float* __restrict__ q, float* __restrict__ k_raw,
    float* __restrict__ v, float* __restrict__ gsig)
{
    // shorts: A-hi [0,4096) A-lo [4096,8192) B-hi [8192,12288) B-lo [12288,16384)
    __shared__ __align__(16) short lds[16384];
    const int cb = blockIdx.x;             // 25 col tiles of 64
    const int tb = blockIdx.y;             // 32 row tiles of 64
    const int w = threadIdx.x >> 6;        // 0..3
    const int l = threadIdx.x & 63;
    const int l16 = l & 15, g4 = l >> 4;
    const int wm = w >> 1, wn = w & 1;
    const int row0 = tb * 64, col0 = cb * 64;

    // staging sources (pre-swizzled): per comp 8KB = 2 passes; per-wave dest
    // byte off within comp: b = p*4096 + w*1024 + l*16
    const short* pA[2][2]; const short* pB[2][2];
    #pragma unroll
    for (int p = 0; p < 2; ++p) {
        int b = p * 4096 + w * 1024 + l * 16;
        int row = b >> 7;                          // 128B per row
        int kb = (b & 127) ^ ((row & 7) << 4);     // inverse swizzle
        pA[0][p] = xhi + (size_t)(row0 + row) * 1024 + (kb >> 1);
        pA[1][p] = xlo + (size_t)(row0 + row) * 1024 + (kb >> 1);
        pB[0][p] = wthi + (size_t)(col0 + row) * 1024 + (kb >> 1);
        pB[1][p] = wtlo + (size_t)(col0 + row) * 1024 + (kb >> 1);
    }

    f32x4 acc[2][2];
    #pragma unroll
    for (int mt = 0; mt < 2; ++mt)
        #pragma unroll
        for (int nt = 0; nt < 2; ++nt) acc[mt][nt] = (f32x4)0.f;

    for (int k0 = 0; k0 < 1024; k0 += 64) {
        #pragma unroll
        for (int p = 0; p < 2; ++p) {
            const int dst = (p * 4096 + w * 1024) >> 1;   // shorts
            GLDS16(pA[0][p] + k0, &lds[dst]);
            GLDS16(pA[1][p] + k0, &lds[4096 + dst]);
            GLDS16(pB[0][p] + k0, &lds[8192 + dst]);
            GLDS16(pB[1][p] + k0, &lds[12288 + dst]);
        }
        __syncthreads();
        #pragma unroll
        for (int ksub = 0; ksub < 2; ++ksub) {
            half8 ah[2], al[2], bh[2], bl[2];
            #pragma unroll
            for (int mt = 0; mt < 2; ++mt) {
                int row = wm * 32 + mt * 16 + l16;
                int kb = (ksub * 64 + g4 * 16) ^ ((row & 7) << 4);
                ah[mt] = *(const half8*)(const void*)&lds[row * 64 + (kb >> 1)];
                al[mt] = *(const half8*)(const void*)&lds[4096 + row * 64 + (kb >> 1)];
            }
            #pragma unroll
            for (int nt = 0; nt < 2; ++nt) {
                int col = wn * 32 + nt * 16 + l16;
                int kb = (ksub * 64 + g4 * 16) ^ ((col & 7) << 4);
                bh[nt] = *(const half8*)(const void*)&lds[8192 + col * 64 + (kb >> 1)];
                bl[nt] = *(const half8*)(const void*)&lds[12288 + col * 64 + (kb >> 1)];
            }
            #pragma unroll
            for (int mt = 0; mt < 2; ++mt)
                #pragma unroll
                for (int nt = 0; nt < 2; ++nt) {
                    acc[mt][nt] = __builtin_amdgcn_mfma_f32_16x16x32_f16(ah[mt], bh[nt], acc[mt][nt], 0, 0, 0);
                    acc[mt][nt] = __builtin_amdgcn_mfma_f32_16x16x32_f16(ah[mt], bl[nt], acc[mt][nt], 0, 0, 0);
                    acc[mt][nt] = __builtin_amdgcn_mfma_f32_16x16x32_f16(al[mt], bh[nt], acc[mt][nt], 0, 0, 0);
                }
        }
        __syncthreads();
    }
    #pragma unroll
    for (int mt = 0; mt < 2; ++mt) {
        #pragma unroll
        for (int r = 0; r < 4; ++r) {
            const int tt = row0 + wm * 32 + mt * 16 + g4 * 4 + r;
            #pragma unroll
            for (int nt = 0; nt < 2; ++nt) {
                const int cg = col0 + wn * 32 + nt * 16 + l16;
                const float val = acc[mt][nt][r];
                if (cg < 1024)      q[(size_t)tt * 1024 + cg] = val;
                else if (cg < 1280) k_raw[(size_t)tt * 256 + cg - 1024] = val;
                else if (cg < 1536) v[(size_t)tt * 256 + cg - 1280] = val;
                else if (cg < 1560) gsig[(size_t)tt * 24 + cg - 1536] = 1.0f / (1.0f + expf(-val));
            }
        }
    }
}

// -------- Kernel 2: fused rope + vtrans + pool -----------------------------
__global__ __launch_bounds__(256) void mid_kernel(
    const float* __restrict__ q, const float* __restrict__ k_raw,
    const float* __restrict__ v_raw, const float* __restrict__ wk_pool,
    const float* __restrict__ wv_pool, const float* __restrict__ pe,
    short* __restrict__ qb, short* __restrict__ krb,
    short* __restrict__ qhi, short* __restrict__ qlo,
    short* __restrict__ vT, short* __restrict__ khi,
    short* __restrict__ klo, short* __restrict__ vcT)
{
    const int bid = blockIdx.x;
    if (bid < 5120) {
        const int t = (bid % 512) * 4 + (threadIdx.x >> 6);
        const int h = bid / 512;
        const int i = threadIdx.x & 63;
        float inv = exp2f(-(float)i * L2INV_);
        float ang = (float)t * inv;
        float sn, cs;
        sincosf(ang, &sn, &cs);
        if (h < 8) {
            const float* p = q + t * 1024 + h * 128;
            float x1 = p[i], x2 = p[i + 64];
            float r1 = x1 * cs - x2 * sn;
            float r2 = x1 * sn + x2 * cs;
            const int o = t * 1024 + h * 128;
            qb[o + i]      = bf16_of(r1);
            qb[o + i + 64] = bf16_of(r2);
            short h1 = f16_of(r1), h2 = f16_of(r2);
            qhi[o + i] = h1;       qlo[o + i]      = f16_of(r1 - f32_of_f16(h1));
            qhi[o + i + 64] = h2;  qlo[o + i + 64] = f16_of(r2 - f32_of_f16(h2));
        } else {
            const float* s = k_raw + t * 256 + (h - 8) * 128;
            float x1 = s[i], x2 = s[i + 64];
            krb[t * 256 + (h - 8) * 128 + i]      = bf16_of(x1 * cs - x2 * sn);
            krb[t * 256 + (h - 8) * 128 + i + 64] = bf16_of(x1 * sn + x2 * cs);
        }
    } else if (bid < 5632) {
        __shared__ short tile[32][33];
        const int b2 = bid - 5120;
        const int s0 = (b2 & 63) * 32, d0 = ((b2 >> 6) & 3) * 32, kv = b2 >> 8;
        const int c = threadIdx.x & 31, r0 = threadIdx.x >> 5;
        #pragma unroll
        for (int rr = 0; rr < 32; rr += 8) {
            int r = r0 + rr;
            tile[r][c] = bf16_of(v_raw[((size_t)(s0 + r) * 2 + kv) * 128 + d0 + c]);
        }
        __syncthreads();
        #pragma unroll
        for (int rr = 0; rr < 32; rr += 8) {
            int r = r0 + rr;
            vT[((size_t)kv * 128 + d0 + r) * 2048 + s0 + c] = tile[c][r];
        }
    } else {
        const int j = bid - 5632;
        const int tid = threadIdx.x;
        const int kv = tid >> 7, d = tid & 127;
        float ak = 0.f, av = 0.f;
        for (int s = 0; s < 32; ++s) {
            float pev = pe[(kv * 32 + s) * 128 + d];
            float kk = k_raw[((j * 32 + s) * 2 + kv) * 128 + d] + pev;
            float vv = v_raw[((j * 32 + s) * 2 + kv) * 128 + d] + pev;
            ak += kk * wk_pool[kv * 32 + s];
            av += vv * wv_pool[kv * 32 + s];
        }
        __shared__ float sk[256];
        sk[tid] = ak;
        __syncthreads();
        int i = d & 63;
        float inv = exp2f(-(float)i * L2INV_);
        float ang = (float)(j * 32) * inv;
        float sn, cs; sincosf(ang, &sn, &cs);
        float x1 = sk[kv * 128 + i], x2 = sk[kv * 128 + i + 64];
        float outv = (d < 64) ? (x1 * cs - x2 * sn) : (x1 * sn + x2 * cs);
        short hi = f16_of(outv);
        khi[(j * 2 + kv) * 128 + d] = hi;
        klo[(j * 2 + kv) * 128 + d] = f16_of(outv - f32_of_f16(hi));
        vcT[((size_t)kv * 128 + d) * 64 + j] = bf16_of(av);
    }
}

// ------- Kernel 4: compressed attention + pw + top-8, (8q,2g)-packed -------
__global__ __launch_bounds__(128) void cmp_mfma_kernel(
    const short* __restrict__ qhi, const short* __restrict__ qlo,
    const short* __restrict__ khi, const short* __restrict__ klo,
    const short* __restrict__ vcT, float* __restrict__ o_cmp,
    unsigned long long* __restrict__ sel_mask)
{
    const int t0 = blockIdx.x * 8;
    const int kv = blockIdx.y;
    const int w  = threadIdx.x >> 6;
    const int l  = threadIdx.x & 63;
    const int l16 = l & 15, g4 = l >> 4;
    const int qq8 = l16 & 7;
    const int gsel = w + 2 * (l16 >> 3);
    __shared__ float pwpart[4][8][68];
    __shared__ __align__(16) short plds[2][16][72];
    const int tq = t0 + qq8;

    half8 qfh[4], qfl[4];
    #pragma unroll
    for (int ks = 0; ks < 4; ++ks) {
        const size_t o = ((size_t)tq * 8 + kv * 4 + gsel) * 128 + ks * 32 + g4 * 8;
        qfh[ks] = *(const half8*)(const void*)(qhi + o);
        qfl[ks] = *(const half8*)(const void*)(qlo + o);
    }
    f32x4 sct[4];
    #pragma unroll
    for (int nt = 0; nt < 4; ++nt) {
        sct[nt] = (f32x4)0.f;
        #pragma unroll
        for (int ks = 0; ks < 4; ++ks) {
            const size_t o = ((size_t)(nt * 16 + l16) * 2 + kv) * 128 + ks * 32 + g4 * 8;
            half8 kfh = *(const half8*)(const void*)(khi + o);
            half8 kfl = *(const half8*)(const void*)(klo + o);
            sct[nt] = __builtin_amdgcn_mfma_f32_16x16x32_f16(kfh, qfh[ks], sct[nt], 0, 0, 0);
            sct[nt] = __builtin_amdgcn_mfma_f32_16x16x32_f16(kfh, qfl[ks], sct[nt], 0, 0, 0);
            sct[nt] = __builtin_amdgcn_mfma_f32_16x16x32_f16(kfl, qfh[ks], sct[nt], 0, 0, 0);
        }
    }
    float p[16];
    float mx = NEGF;
    #pragma unroll
    for (int nt = 0; nt < 4; ++nt)
        #pragma unroll
        for (int r = 0; r < 4; ++r) {
            const int j = nt * 16 + g4 * 4 + r;
            const bool vis = (tq >= j * 32 + 31);
            const float sv = vis ? sct[nt][r] * SCALE_ : NEGF;
            p[nt * 4 + r] = sv;
            mx = fmaxf(mx, sv);
        }
    mx = fmaxf(mx, __shfl_xor(mx, 16, 64));
    mx = fmaxf(mx, __shfl_xor(mx, 32, 64));
    float rs = 0.f;
    #pragma unroll
    for (int i = 0; i < 16; ++i) {
        float pv = (p[i] > -1e29f) ? __expf(p[i] - mx) : 0.f;
        p[i] = pv;
        rs += pv;
    }
    rs += __shfl_xor(rs, 16, 64);
    rs += __shfl_xor(rs, 32, 64);
    const float rl = (rs > 0.f) ? 1.0f / rs : 0.f;
    #pragma unroll
    for (int nt = 0; nt < 4; ++nt)
        #pragma unroll
        for (int r = 0; r < 4; ++r) {
            const int j = nt * 16 + g4 * 4 + r;
            pwpart[gsel][qq8][j] = p[nt * 4 + r] * rl;
            plds[w][l16][j]      = bf16_of(p[nt * 4 + r]);
        }
    short8 pa0 = *(const short8*)(&plds[w][l16][g4 * 8]);
    short8 pa1 = *(const short8*)(&plds[w][l16][32 + g4 * 8]);
    f32x4 acc[8];
    #pragma unroll
    for (int dt = 0; dt < 8; ++dt) {
        const short* vr = vcT + ((size_t)kv * 128 + dt * 16 + l16) * 64;
        short8 vf0 = *(const short8*)(vr + g4 * 8);
        short8 vf1 = *(const short8*)(vr + 32 + g4 * 8);
        acc[dt] = (f32x4)0.f;
        acc[dt] = __builtin_amdgcn_mfma_f32_16x16x32_bf16(vf0, pa0, acc[dt], 0, 0, 0);
        acc[dt] = __builtin_amdgcn_mfma_f32_16x16x32_bf16(vf1, pa1, acc[dt], 0, 0, 0);
    }
    #pragma unroll
    for (int dt = 0; dt < 8; ++dt)
        #pragma unroll
        for (int r = 0; r < 4; ++r)
            o_cmp[(size_t)tq * 1024 + (kv * 4 + gsel) * 128 + dt * 16 + g4 * 4 + r] = acc[dt][r] * rl;
    __syncthreads();
    const int j = l;
    for (int qi = 0; qi < 4; ++qi) {
        const int qq = w * 4 + qi;
        const int tqq = t0 + qq;
        float pw = pwpart[0][qq][j] + pwpart[1][qq][j]
                 + pwpart[2][qq][j] + pwpart[3][qq][j];
        const int cur = tqq >> 5;
        const int curm1 = cur > 0 ? cur - 1 : 0;
        const bool forced = (j == 0) || (j == cur) || (j == curm1);
        const bool allowed = (j * 32 <= tqq);
        float sc = allowed ? (pw + (forced ? BIGF : 0.f)) : -1.0f;
        unsigned long long selm = 0ull;
        for (int it = 0; it < 8; ++it) {
            float bv = sc; int bi = j;
            #pragma unroll
            for (int off = 32; off >= 1; off >>= 1) {
                float ov = __shfl_xor(bv, off, 64);
                int   oi = __shfl_xor(bi, off, 64);
                if (ov > bv || (ov == bv && oi < bi)) { bv = ov; bi = oi; }
            }
            if (bv > -0.5f) selm |= (1ull << bi);
            if (j == bi) sc = -3e38f;
        }
        if (l == 0) sel_mask[(size_t)tqq * 2 + kv] = selm;
    }
}

// ------- Kernel 5a: slc+swa split-K, staged single-buffer K/V --------------
__global__ __launch_bounds__(64, 2) void slcswa_part_kernel(
    const short* __restrict__ qb, const short* __restrict__ krb,
    const short* __restrict__ vT, const unsigned long long* __restrict__ sel,
    short* __restrict__ slc_part, float2* __restrict__ ml_slc,
    short* __restrict__ swa_part, float2* __restrict__ ml_swa)
{
    const int t0 = (511 - blockIdx.x) * QT;     // LPT: big lists first
    const int kv = blockIdx.y;
    const int sid = blockIdx.z;                 // 0..1
    const int l  = threadIdx.x;
    const int l16 = l & 15, g4 = l >> 4;
    const int qq = l16 & 3;
    const int gg = l16 >> 2;
    __shared__ __align__(16) short kbuf[4096];
    __shared__ __align__(16) short vbuf[4096];
    __shared__ __align__(16) short plds[16][40];
    __shared__ int list_s0[48];
    __shared__ unsigned long long qm[QT];
    __shared__ int ne_s, nslc_s;

    if (l < QT) qm[l] = sel[(size_t)(t0 + l) * 2 + kv];
    __syncthreads();
    if (l == 0) {
        unsigned long long u = qm[0] | qm[1] | qm[2] | qm[3];
        int n = 0;
        while (u) { int j = __ffsll((long long)u) - 1; list_s0[n++] = j * 32; u &= u - 1; }
        nslc_s = n;
        int sLo = (t0 >= 256) ? ((t0 - 256) & ~31) : 0;
        for (int s0 = sLo; s0 <= t0 + QT - 1; s0 += 32) list_s0[n++] = s0;
        ne_s = n;
    }
    __syncthreads();
    const int nslc = nslc_s, ne = ne_s;

    const int tq = t0 + qq;
    const unsigned long long myqm = qm[qq];
    short8 qf[4];
    #pragma unroll
    for (int ks = 0; ks < 4; ++ks)
        qf[ks] = *(const short8*)(qb + ((size_t)tq * 8 + kv * 4 + gg) * 128 + ks * 32 + g4 * 8);

    #define STAGE_K(s0v)                                                          \
    {                                                                             \
        _Pragma("unroll")                                                         \
        for (int ps = 0; ps < 8; ++ps) {                                          \
            int off = ps * 1024 + (l << 4);                                       \
            int row = off >> 8, col = off & 255;                                  \
            int cs = col ^ ((row & 7) << 4);                                      \
            GLDS16(krb + (((size_t)((s0v) + row) * 2 + kv) << 7) + (cs >> 1),     \
                   &kbuf[ps * 512]);                                              \
        }                                                                         \
    }
    #define STAGE_V(s0v)                                                          \
    {                                                                             \
        _Pragma("unroll")                                                         \
        for (int ps = 0; ps < 8; ++ps) {                                          \
            int off = ps * 1024 + (l << 4);                                       \
            int row = off >> 6, col = off & 63;                                   \
            int cs = col ^ (((row >> 1) & 3) << 4);                               \
            GLDS16(vT + (size_t)(kv * 128 + row) * 2048 + (s0v) + (cs >> 1),      \
                   &vbuf[ps * 512]);                                              \
        }                                                                         \
    }

    f32x4 acc[8];
    #pragma unroll
    for (int dt = 0; dt < 8; ++dt) acc[dt] = (f32x4)0.f;
    float m_r = NEGF, l_r = 0.f;

    const size_t pbase = (size_t)(((sid * 2048 + tq) * 2 + kv) * 4 + gg) * 128;
    const int mlidx = ((sid * 2048 + tq) * 2 + kv) * 4 + gg;

    if (sid >= nslc) {
        #pragma unroll
        for (int dt = 0; dt < 8; ++dt)
            *(short4v*)(slc_part + pbase + dt * 16 + g4 * 4) = (short4v){0,0,0,0};
        if (g4 == 0) ml_slc[mlidx] = make_float2(NEGF, 0.f);
    }

    if (sid < ne) {
        STAGE_K(list_s0[sid]);
        STAGE_V(list_s0[sid]);
    }

    for (int e = sid; e < ne; e += 2) {
        const int s0 = list_s0[e];
        const int md = (e >= nslc);
        const bool has_next = (e + 2 < ne);

        asm volatile("s_waitcnt vmcnt(8)" ::: "memory");
        f32x4 sct[2];
        sct[0] = (f32x4)0.f; sct[1] = (f32x4)0.f;
        #pragma unroll
        for (int nt = 0; nt < 2; ++nt) {
            const int row = nt * 16 + l16;
            short8 kf[4];
            #pragma unroll
            for (int ks = 0; ks < 4; ++ks)
                kf[ks] = *(const short8*)&kbuf[row * 128 + ((((ks * 64 + g4 * 16) ^ ((row & 7) << 4))) >> 1)];
            #pragma unroll
            for (int ks = 0; ks < 4; ++ks)
                sct[nt] = __builtin_amdgcn_mfma_f32_16x16x32_bf16(kf[ks], qf[ks], sct[nt], 0, 0, 0);
        }
        asm volatile("s_waitcnt lgkmcnt(0)" ::: "memory");
        if (has_next) STAGE_K(list_s0[e + 2]);

        const bool inm = md ? true : ((myqm >> (s0 >> 5)) & 1ull);
        float p[8];
        float mx = NEGF;
        #pragma unroll
        for (int nt = 0; nt < 2; ++nt)
            #pragma unroll
            for (int r = 0; r < 4; ++r) {
                const int key = s0 + nt * 16 + g4 * 4 + r;
                const bool vv = md ? ((key <= tq) && (key >= tq - 256))
                                   : (inm && (key <= tq));
                const float sv = vv ? sct[nt][r] * SCALE_ : NEGF;
                p[nt * 4 + r] = sv;
                mx = fmaxf(mx, sv);
            }
        mx = fmaxf(mx, __shfl_xor(mx, 16, 64));
        mx = fmaxf(mx, __shfl_xor(mx, 32, 64));
        if (!__all(mx <= m_r + 8.0f)) {
            const float mnew = fmaxf(m_r, mx);
            const float alx = __expf(m_r - mnew);
            l_r *= alx;
            m_r = mnew;
            #pragma unroll
            for (int dt = 0; dt < 8; ++dt) acc[dt] *= alx;
        }
        float rs = 0.f;
        #pragma unroll
        for (int i = 0; i < 8; ++i) {
            float pv = (p[i] > -1e29f) ? __expf(p[i] - m_r) : 0.f;
            p[i] = pv; rs += pv;
        }
        rs += __shfl_xor(rs, 16, 64);
        rs += __shfl_xor(rs, 32, 64);
        l_r += rs;
        short4v pk0, pk1;
        #pragma unroll
        for (int r = 0; r < 4; ++r) { pk0[r] = bf16_of(p[r]); pk1[r] = bf16_of(p[4 + r]); }
        *(short4v*)&plds[l16][g4 * 4]      = pk0;
        *(short4v*)&plds[l16][16 + g4 * 4] = pk1;
        short8 pa = *(const short8*)(&plds[l16][g4 * 8]);

        if (has_next) { asm volatile("s_waitcnt vmcnt(8)" ::: "memory"); }
        else          { asm volatile("s_waitcnt vmcnt(0)" ::: "memory"); }
        #pragma unroll
        for (int dt = 0; dt < 8; ++dt) {
            const int row = dt * 16 + l16;
            short8 vf = *(const short8*)&vbuf[row * 32 + (((g4 * 16) ^ (((row >> 1) & 3) << 4)) >> 1)];
            acc[dt] = __builtin_amdgcn_mfma_f32_16x16x32_bf16(vf, pa, acc[dt], 0, 0, 0);
        }
        asm volatile("s_waitcnt lgkmcnt(0)" ::: "memory");
        if (has_next) STAGE_V(list_s0[e + 2]);

        if (!md && e + 2 >= nslc) {
            #pragma unroll
            for (int dt = 0; dt < 8; ++dt) {
                short4v pk;
                #pragma unroll
                for (int r = 0; r < 4; ++r) pk[r] = bf16_of(acc[dt][r]);
                *(short4v*)(slc_part + pbase + dt * 16 + g4 * 4) = pk;
                acc[dt] = (f32x4)0.f;
            }
            if (g4 == 0) ml_slc[mlidx] = make_float2(m_r, l_r);
            m_r = NEGF; l_r = 0.f;
        }
    }

    #pragma unroll
    for (int dt = 0; dt < 8; ++dt) {
        short4v pk;
        #pragma unroll
        for (int r = 0; r < 4; ++r) pk[r] = bf16_of(acc[dt][r]);
        *(short4v*)(swa_part + pbase + dt * 16 + g4 * 4) = pk;
    }
    if (g4 == 0) ml_swa[mlidx] = make_float2(m_r, l_r);
    #undef STAGE_K
    #undef STAGE_V
}

// ------- Kernel 5b: merge 2 splits + gated combine -------------------------
__global__ __launch_bounds__(256) void merge_kernel(
    const short* __restrict__ slc_part, const float2* __restrict__ ml_slc,
    const short* __restrict__ swa_part, const float2* __restrict__ ml_swa,
    const float* __restrict__ gsig, const float* __restrict__ o_cmp,
    float* __restrict__ out)
{
    const int t0 = blockIdx.x * 8;
    const int kv = blockIdx.y;
    for (int base = threadIdx.x * 4; base < 8 * 512; base += 256 * 4) {
        const int q_ = base >> 9, c = base & 511;
        const int gg = c >> 7, d = c & 127;
        const int tq = t0 + q_;
        const int mi0 = (tq * 2 + kv) * 4 + gg;
        const int mi1 = ((2048 + tq) * 2 + kv) * 4 + gg;
        float2 s0m = ml_slc[mi0], s1m = ml_slc[mi1];
        float M = fmaxf(s0m.x, s1m.x);
        float a0 = __expf(s0m.x - M), a1 = __expf(s1m.x - M);
        float L = s0m.y * a0 + s1m.y * a1;
        float rL = (L > 0.f) ? 1.0f / L : 0.f;
        short4v p0 = *(const short4v*)(slc_part + (size_t)mi0 * 128 + d);
        short4v p1 = *(const short4v*)(slc_part + (size_t)mi1 * 128 + d);
        float2 w0m = ml_swa[mi0], w1m = ml_swa[mi1];
        float Mw = fmaxf(w0m.x, w1m.x);
        float b0 = __expf(w0m.x - Mw), b1 = __expf(w1m.x - Mw);
        float Lw = w0m.y * b0 + w1m.y * b1;
        float rLw = (Lw > 0.f) ? 1.0f / Lw : 0.f;
        short4v q0 = *(const short4v*)(swa_part + (size_t)mi0 * 128 + d);
        short4v q1 = *(const short4v*)(swa_part + (size_t)mi1 * 128 + d);
        const float gc = gsig[(size_t)tq * 24 + kv * 12 + gg * 3 + 0];
        const float gs = gsig[(size_t)tq * 24 + kv * 12 + gg * 3 + 1];
        const float gw = gsig[(size_t)tq * 24 + kv * 12 + gg * 3 + 2];
        const size_t oi = (size_t)tq * 1024 + (kv * 4 + gg) * 128 + d;
        float4 oc = *(const float4*)(o_cmp + oi);
        float ocv[4] = {oc.x, oc.y, oc.z, oc.w};
        float res[4];
        #pragma unroll
        for (int r = 0; r < 4; ++r) {
            float oslc = (f32_of_bf16bits((unsigned short)p0[r]) * a0
                        + f32_of_bf16bits((unsigned short)p1[r]) * a1) * rL;
            float oswa = (f32_of_bf16bits((unsigned short)q0[r]) * b0
                        + f32_of_bf16bits((unsigned short)q1[r]) * b1) * rLw;
            res[r] = gc * ocv[r] + gs * oslc + gw * oswa;
        }
        float4 o4;
        o4.x = res[0]; o4.y = res[1]; o4.z = res[2]; o4.w = res[3];
        *(float4*)(out + oi) = o4;
    }
}

extern "C" void kernel_launch(void* const* d_in, const int* in_sizes, int n_in,
                              void* d_out, int out_size, void* d_ws, size_t ws_size,
                              hipStream_t stream)
{
    const float* x       = (const float*)d_in[0];
    const float* Wq      = (const float*)d_in[1];
    const float* Wk      = (const float*)d_in[2];
    const float* Wv      = (const float*)d_in[3];
    const float* Wg      = (const float*)d_in[4];
    const float* wk_pool = (const float*)d_in[5];
    const float* wv_pool = (const float*)d_in[6];
    const float* pe      = (const float*)d_in[7];
    float* out = (float*)d_out;
    float* ws  = (float*)d_ws;

    // ---- workspace layout (floats); ~45 MB ----
    float* q     = ws;                         // 2,097,152
    float* k_raw = q + 2097152;                //   524,288
    float* v     = k_raw + 524288;             //   524,288
    float* gsig  = v + 524288;                 //    49,152
    unsigned long long* sel = (unsigned long long*)(gsig + 49152); // 8,192 f
    float* o_cmp = (float*)sel + 8192;         // 2,097,152
    short* xhi   = (short*)o_cmp;              // alias o_cmp (dead before cmp writes)
    short* xlo   = xhi + 2097152;
    short* qb    = (short*)(o_cmp + 2097152);  // 2,097,152 sh
    short* krb   = qb + 2097152;               //   524,288 sh
    short* vT    = krb + 524288;               //   524,288 sh
    short* khi   = vT + 524288;                //    16,384 sh
    short* klo   = khi + 16384;                //    16,384 sh
    short* vcT   = klo + 16384;                //    16,384 sh
    short* wthi  = qb;                         // alias qb.. (dead before rope/pool)
    short* wtlo  = wthi + 1638400;             // spans krb/vT/pad
    short* qhi   = qb + 3276800;               // 2,097,152 sh (after wtlo end)
    short* qlo   = qhi + 2097152;              // 2,097,152 sh
    short* slc_part = qhi;                     // 4,194,304 sh (alias qhi+qlo)
    short* swa_part = qlo + 2097152;           // 4,194,304 sh
    float2* ml_slc  = (float2*)(swa_part + 4194304); // 32,768 float2
    float2* ml_swa  = ml_slc + 32768;                // 32,768 float2

    hipLaunchKernelGGL(prep_kernel, dim3(3648), dim3(256), 0, stream,
                       x, Wq, Wk, Wv, Wg, xhi, xlo, wthi, wtlo);
    hipLaunchKernelGGL(proj_mfma_kernel, dim3(25, 32), dim3(256), 0, stream,
                       xhi, xlo, wthi, wtlo, q, k_raw, v, gsig);
    hipLaunchKernelGGL(mid_kernel, dim3(5696), dim3(256), 0, stream,
                       q, k_raw, v, wk_pool, wv_pool, pe,
                       qb, krb, qhi, qlo, vT, khi, klo, vcT);
    hipLaunchKernelGGL(cmp_mfma_kernel, dim3(256, 2), dim3(128), 0, stream,
                       qhi, qlo, khi, klo, vcT, o_cmp, sel);
    hipLaunchKernelGGL(slcswa_part_kernel, dim3(512, 2, 2), dim3(64), 0, stream,
                       qb, krb, vT, sel, slc_part, ml_slc, swa_part, ml_swa);
    hipLaunchKernelGGL(merge_kernel, dim3(256, 2), dim3(256), 0, stream,
                       slc_part, ml_slc, swa_part, ml_swa, gsig, o_cmp, out);
}

// Round 20
// 117.386 us; speedup vs baseline: 1.0466x; 1.0466x over previous
//
#include <hip/hip_runtime.h>
#include <math.h>

#define NEGF  (-1e30f)
#define BIGF  (1000000.0f)
#define SCALE_ (0.08838834764831845f)   // 1/sqrt(128)
#define L2INV_ (0.20762050593046014f)   // log2(10000)/64
#define QT 4

typedef __attribute__((ext_vector_type(4))) float f32x4;
typedef __attribute__((ext_vector_type(8))) short short8;
typedef __attribute__((ext_vector_type(4))) short short4v;
typedef __attribute__((ext_vector_type(8))) _Float16 half8;

#define GLDS16(gp, lp) __builtin_amdgcn_global_load_lds( \
    (const __attribute__((address_space(1))) void*)(gp), \
    (__attribute__((address_space(3))) void*)(lp), 16, 0, 0)

__device__ __forceinline__ short bf16_of(float f) {
    union { float f; unsigned u; } x; x.f = f;
    unsigned r = x.u + 0x7fffu + ((x.u >> 16) & 1u);
    return (short)(r >> 16);
}
__device__ __forceinline__ float f32_of_bf16bits(unsigned u16) {
    union { unsigned u; float f; } x; x.u = u16 << 16;
    return x.f;
}
__device__ __forceinline__ short f16_of(float f) {
    _Float16 h = (_Float16)f;
    union { _Float16 h; short s; } u; u.h = h;
    return u.s;
}
__device__ __forceinline__ float f32_of_f16(short s) {
    union { _Float16 h; short s; } u; u.s = s;
    return (float)u.h;
}

// -------- Kernel 0: fused xconv + wconv ------------------------------------
__global__ __launch_bounds__(256) void prep_kernel(
    const float* __restrict__ x, const float* __restrict__ Wq,
    const float* __restrict__ Wk, const float* __restrict__ Wv,
    const float* __restrict__ Wg, short* __restrict__ xhi,
    short* __restrict__ xlo, short* __restrict__ wthi, short* __restrict__ wtlo)
{
    const int bid = blockIdx.x;
    if (bid < 2048) {
        const int i = bid * 1024 + threadIdx.x * 4;
        float4 f = *(const float4*)(x + i);
        short4v hi, lo;
        float fv[4] = {f.x, f.y, f.z, f.w};
        #pragma unroll
        for (int c = 0; c < 4; ++c) {
            short h = f16_of(fv[c]);
            hi[c] = h;
            lo[c] = f16_of(fv[c] - f32_of_f16(h));
        }
        *(short4v*)(xhi + i) = hi;
        *(short4v*)(xlo + i) = lo;
    } else {
        __shared__ float tile[32][33];
        const int b2 = bid - 2048;
        const int ct = b2 % 50, kt = b2 / 50;
        const int c = threadIdx.x & 31, r0 = threadIdx.x >> 5;
        #pragma unroll
        for (int rr = 0; rr < 32; rr += 8) {
            int k = kt * 32 + r0 + rr;
            int gc = ct * 32 + c;
            float val;
            if (gc < 1024)      val = Wq[k * 1024 + gc];
            else if (gc < 1280) val = Wk[k * 256 + gc - 1024];
            else if (gc < 1536) val = Wv[k * 256 + gc - 1280];
            else if (gc < 1560) val = Wg[k * 24 + gc - 1536];
            else                val = 0.f;
            tile[r0 + rr][c] = val;
        }
        __syncthreads();
        #pragma unroll
        for (int rr = 0; rr < 32; rr += 8) {
            int col = ct * 32 + r0 + rr;
            int k = kt * 32 + c;
            float val = tile[c][r0 + rr];
            short hi = f16_of(val);
            short lo = f16_of(val - f32_of_f16(hi));
            wthi[(size_t)col * 1024 + k] = hi;
            wtlo[(size_t)col * 1024 + k] = lo;
        }
    }
}

// -------- Kernel 1: projections via split-fp16 MFMA, LDS-staged ------------
__global__ __launch_bounds__(512, 2) void proj_mfma_kernel(
    const short* __restrict__ xhi, const short* __restrict__ xlo,
    const short* __restrict__ wthi, const short* __restrict__ wtlo,
    float* __restrict__ q, float* __restrict__ k_raw,
    float* __restrict__ v, float* __restrict__ gsig)
{
    __shared__ __align__(16) short lds[24576];
    const int cb = blockIdx.x;
    const int tb = blockIdx.y;
    const int w = threadIdx.x >> 6;
    const int l = threadIdx.x & 63;
    const int l16 = l & 15, g4 = l >> 4;
    const int wm = w >> 1, wn = w & 1;
    const int row0 = tb * 128, col0 = cb * 64;

    const short* pAhi[2]; const short* pAlo[2];
    #pragma unroll
    for (int j = 0; j < 2; ++j) {
        int b = (2 * w + j) * 1024 + l * 16;
        int row = b >> 7;
        int kb = (b & 127) ^ ((row & 7) << 4);
        pAhi[j] = xhi + (size_t)(row0 + row) * 1024 + (kb >> 1);
        pAlo[j] = xlo + (size_t)(row0 + row) * 1024 + (kb >> 1);
    }
    const short* pBhi; const short* pBlo;
    {
        int b = w * 1024 + l * 16;
        int col = b >> 7;
        int kb = (b & 127) ^ ((col & 7) << 4);
        pBhi = wthi + (size_t)(col0 + col) * 1024 + (kb >> 1);
        pBlo = wtlo + (size_t)(col0 + col) * 1024 + (kb >> 1);
    }

    f32x4 acc[2][2];
    #pragma unroll
    for (int mt = 0; mt < 2; ++mt)
        #pragma unroll
        for (int nt = 0; nt < 2; ++nt) acc[mt][nt] = (f32x4)0.f;

    for (int k0 = 0; k0 < 1024; k0 += 64) {
        GLDS16(pAhi[0] + k0, &lds[(2 * w + 0) * 512]);
        GLDS16(pAhi[1] + k0, &lds[(2 * w + 1) * 512]);
        GLDS16(pAlo[0] + k0, &lds[8192 + (2 * w + 0) * 512]);
        GLDS16(pAlo[1] + k0, &lds[8192 + (2 * w + 1) * 512]);
        GLDS16(pBhi + k0,    &lds[16384 + w * 512]);
        GLDS16(pBlo + k0,    &lds[20480 + w * 512]);
        __syncthreads();
        #pragma unroll
        for (int ksub = 0; ksub < 2; ++ksub) {
            half8 ah[2], al[2], bh[2], bl[2];
            #pragma unroll
            for (int mt = 0; mt < 2; ++mt) {
                int row = wm * 32 + mt * 16 + l16;
                int kb = (ksub * 64 + g4 * 16) ^ ((row & 7) << 4);
                ah[mt] = *(const half8*)(const void*)&lds[row * 64 + (kb >> 1)];
                al[mt] = *(const half8*)(const void*)&lds[8192 + row * 64 + (kb >> 1)];
            }
            #pragma unroll
            for (int nt = 0; nt < 2; ++nt) {
                int col = wn * 32 + nt * 16 + l16;
                int kb = (ksub * 64 + g4 * 16) ^ ((col & 7) << 4);
                bh[nt] = *(const half8*)(const void*)&lds[16384 + col * 64 + (kb >> 1)];
                bl[nt] = *(const half8*)(const void*)&lds[20480 + col * 64 + (kb >> 1)];
            }
            #pragma unroll
            for (int mt = 0; mt < 2; ++mt)
                #pragma unroll
                for (int nt = 0; nt < 2; ++nt) {
                    acc[mt][nt] = __builtin_amdgcn_mfma_f32_16x16x32_f16(ah[mt], bh[nt], acc[mt][nt], 0, 0, 0);
                    acc[mt][nt] = __builtin_amdgcn_mfma_f32_16x16x32_f16(ah[mt], bl[nt], acc[mt][nt], 0, 0, 0);
                    acc[mt][nt] = __builtin_amdgcn_mfma_f32_16x16x32_f16(al[mt], bh[nt], acc[mt][nt], 0, 0, 0);
                }
        }
        __syncthreads();
    }
    #pragma unroll
    for (int mt = 0; mt < 2; ++mt) {
        #pragma unroll
        for (int r = 0; r < 4; ++r) {
            const int tt = row0 + wm * 32 + mt * 16 + g4 * 4 + r;
            #pragma unroll
            for (int nt = 0; nt < 2; ++nt) {
                const int cg = col0 + wn * 32 + nt * 16 + l16;
                const float val = acc[mt][nt][r];
                if (cg < 1024)      q[(size_t)tt * 1024 + cg] = val;
                else if (cg < 1280) k_raw[(size_t)tt * 256 + cg - 1024] = val;
                else if (cg < 1536) v[(size_t)tt * 256 + cg - 1280] = val;
                else if (cg < 1560) gsig[(size_t)tt * 24 + cg - 1536] = 1.0f / (1.0f + expf(-val));
            }
        }
    }
}

// -------- Kernel 2: fused rope + vtrans + pool -----------------------------
__global__ __launch_bounds__(256) void mid_kernel(
    const float* __restrict__ q, const float* __restrict__ k_raw,
    const float* __restrict__ v_raw, const float* __restrict__ wk_pool,
    const float* __restrict__ wv_pool, const float* __restrict__ pe,
    short* __restrict__ qb, short* __restrict__ krb,
    short* __restrict__ qhi, short* __restrict__ qlo,
    short* __restrict__ vT, short* __restrict__ khi,
    short* __restrict__ klo, short* __restrict__ vcT)
{
    const int bid = blockIdx.x;
    if (bid < 5120) {
        const int t = (bid % 512) * 4 + (threadIdx.x >> 6);
        const int h = bid / 512;
        const int i = threadIdx.x & 63;
        float inv = exp2f(-(float)i * L2INV_);
        float ang = (float)t * inv;
        float sn, cs;
        sincosf(ang, &sn, &cs);
        if (h < 8) {
            const float* p = q + t * 1024 + h * 128;
            float x1 = p[i], x2 = p[i + 64];
            float r1 = x1 * cs - x2 * sn;
            float r2 = x1 * sn + x2 * cs;
            const int o = t * 1024 + h * 128;
            qb[o + i]      = bf16_of(r1);
            qb[o + i + 64] = bf16_of(r2);
            short h1 = f16_of(r1), h2 = f16_of(r2);
            qhi[o + i] = h1;       qlo[o + i]      = f16_of(r1 - f32_of_f16(h1));
            qhi[o + i + 64] = h2;  qlo[o + i + 64] = f16_of(r2 - f32_of_f16(h2));
        } else {
            const float* s = k_raw + t * 256 + (h - 8) * 128;
            float x1 = s[i], x2 = s[i + 64];
            krb[t * 256 + (h - 8) * 128 + i]      = bf16_of(x1 * cs - x2 * sn);
            krb[t * 256 + (h - 8) * 128 + i + 64] = bf16_of(x1 * sn + x2 * cs);
        }
    } else if (bid < 5632) {
        __shared__ short tile[32][33];
        const int b2 = bid - 5120;
        const int s0 = (b2 & 63) * 32, d0 = ((b2 >> 6) & 3) * 32, kv = b2 >> 8;
        const int c = threadIdx.x & 31, r0 = threadIdx.x >> 5;
        #pragma unroll
        for (int rr = 0; rr < 32; rr += 8) {
            int r = r0 + rr;
            tile[r][c] = bf16_of(v_raw[((size_t)(s0 + r) * 2 + kv) * 128 + d0 + c]);
        }
        __syncthreads();
        #pragma unroll
        for (int rr = 0; rr < 32; rr += 8) {
            int r = r0 + rr;
            vT[((size_t)kv * 128 + d0 + r) * 2048 + s0 + c] = tile[c][r];
        }
    } else {
        const int j = bid - 5632;
        const int tid = threadIdx.x;
        const int kv = tid >> 7, d = tid & 127;
        float ak = 0.f, av = 0.f;
        for (int s = 0; s < 32; ++s) {
            float pev = pe[(kv * 32 + s) * 128 + d];
            float kk = k_raw[((j * 32 + s) * 2 + kv) * 128 + d] + pev;
            float vv = v_raw[((j * 32 + s) * 2 + kv) * 128 + d] + pev;
            ak += kk * wk_pool[kv * 32 + s];
            av += vv * wv_pool[kv * 32 + s];
        }
        __shared__ float sk[256];
        sk[tid] = ak;
        __syncthreads();
        int i = d & 63;
        float inv = exp2f(-(float)i * L2INV_);
        float ang = (float)(j * 32) * inv;
        float sn, cs; sincosf(ang, &sn, &cs);
        float x1 = sk[kv * 128 + i], x2 = sk[kv * 128 + i + 64];
        float outv = (d < 64) ? (x1 * cs - x2 * sn) : (x1 * sn + x2 * cs);
        short hi = f16_of(outv);
        khi[(j * 2 + kv) * 128 + d] = hi;
        klo[(j * 2 + kv) * 128 + d] = f16_of(outv - f32_of_f16(hi));
        vcT[((size_t)kv * 128 + d) * 64 + j] = bf16_of(av);
    }
}

// ------- Kernel 4: compressed attention + pw + top-8, (8q,2g)-packed -------
__global__ __launch_bounds__(128) void cmp_mfma_kernel(
    const short* __restrict__ qhi, const short* __restrict__ qlo,
    const short* __restrict__ khi, const short* __restrict__ klo,
    const short* __restrict__ vcT, float* __restrict__ o_cmp,
    unsigned long long* __restrict__ sel_mask)
{
    const int t0 = blockIdx.x * 8;
    const int kv = blockIdx.y;
    const int w  = threadIdx.x >> 6;
    const int l  = threadIdx.x & 63;
    const int l16 = l & 15, g4 = l >> 4;
    const int qq8 = l16 & 7;
    const int gsel = w + 2 * (l16 >> 3);
    __shared__ float pwpart[4][8][68];
    __shared__ __align__(16) short plds[2][16][72];
    const int tq = t0 + qq8;

    half8 qfh[4], qfl[4];
    #pragma unroll
    for (int ks = 0; ks < 4; ++ks) {
        const size_t o = ((size_t)tq * 8 + kv * 4 + gsel) * 128 + ks * 32 + g4 * 8;
        qfh[ks] = *(const half8*)(const void*)(qhi + o);
        qfl[ks] = *(const half8*)(const void*)(qlo + o);
    }
    f32x4 sct[4];
    #pragma unroll
    for (int nt = 0; nt < 4; ++nt) {
        sct[nt] = (f32x4)0.f;
        #pragma unroll
        for (int ks = 0; ks < 4; ++ks) {
            const size_t o = ((size_t)(nt * 16 + l16) * 2 + kv) * 128 + ks * 32 + g4 * 8;
            half8 kfh = *(const half8*)(const void*)(khi + o);
            half8 kfl = *(const half8*)(const void*)(klo + o);
            sct[nt] = __builtin_amdgcn_mfma_f32_16x16x32_f16(kfh, qfh[ks], sct[nt], 0, 0, 0);
            sct[nt] = __builtin_amdgcn_mfma_f32_16x16x32_f16(kfh, qfl[ks], sct[nt], 0, 0, 0);
            sct[nt] = __builtin_amdgcn_mfma_f32_16x16x32_f16(kfl, qfh[ks], sct[nt], 0, 0, 0);
        }
    }
    float p[16];
    float mx = NEGF;
    #pragma unroll
    for (int nt = 0; nt < 4; ++nt)
        #pragma unroll
        for (int r = 0; r < 4; ++r) {
            const int j = nt * 16 + g4 * 4 + r;
            const bool vis = (tq >= j * 32 + 31);
            const float sv = vis ? sct[nt][r] * SCALE_ : NEGF;
            p[nt * 4 + r] = sv;
            mx = fmaxf(mx, sv);
        }
    mx = fmaxf(mx, __shfl_xor(mx, 16, 64));
    mx = fmaxf(mx, __shfl_xor(mx, 32, 64));
    float rs = 0.f;
    #pragma unroll
    for (int i = 0; i < 16; ++i) {
        float pv = (p[i] > -1e29f) ? __expf(p[i] - mx) : 0.f;
        p[i] = pv;
        rs += pv;
    }
    rs += __shfl_xor(rs, 16, 64);
    rs += __shfl_xor(rs, 32, 64);
    const float rl = (rs > 0.f) ? 1.0f / rs : 0.f;
    #pragma unroll
    for (int nt = 0; nt < 4; ++nt)
        #pragma unroll
        for (int r = 0; r < 4; ++r) {
            const int j = nt * 16 + g4 * 4 + r;
            pwpart[gsel][qq8][j] = p[nt * 4 + r] * rl;
            plds[w][l16][j]      = bf16_of(p[nt * 4 + r]);
        }
    short8 pa0 = *(const short8*)(&plds[w][l16][g4 * 8]);
    short8 pa1 = *(const short8*)(&plds[w][l16][32 + g4 * 8]);
    f32x4 acc[8];
    #pragma unroll
    for (int dt = 0; dt < 8; ++dt) {
        const short* vr = vcT + ((size_t)kv * 128 + dt * 16 + l16) * 64;
        short8 vf0 = *(const short8*)(vr + g4 * 8);
        short8 vf1 = *(const short8*)(vr + 32 + g4 * 8);
        acc[dt] = (f32x4)0.f;
        acc[dt] = __builtin_amdgcn_mfma_f32_16x16x32_bf16(vf0, pa0, acc[dt], 0, 0, 0);
        acc[dt] = __builtin_amdgcn_mfma_f32_16x16x32_bf16(vf1, pa1, acc[dt], 0, 0, 0);
    }
    #pragma unroll
    for (int dt = 0; dt < 8; ++dt)
        #pragma unroll
        for (int r = 0; r < 4; ++r)
            o_cmp[(size_t)tq * 1024 + (kv * 4 + gsel) * 128 + dt * 16 + g4 * 4 + r] = acc[dt][r] * rl;
    __syncthreads();
    const int j = l;
    for (int qi = 0; qi < 4; ++qi) {
        const int qq = w * 4 + qi;
        const int tqq = t0 + qq;
        float pw = pwpart[0][qq][j] + pwpart[1][qq][j]
                 + pwpart[2][qq][j] + pwpart[3][qq][j];
        const int cur = tqq >> 5;
        const int curm1 = cur > 0 ? cur - 1 : 0;
        const bool forced = (j == 0) || (j == cur) || (j == curm1);
        const bool allowed = (j * 32 <= tqq);
        float sc = allowed ? (pw + (forced ? BIGF : 0.f)) : -1.0f;
        unsigned long long selm = 0ull;
        for (int it = 0; it < 8; ++it) {
            float bv = sc; int bi = j;
            #pragma unroll
            for (int off = 32; off >= 1; off >>= 1) {
                float ov = __shfl_xor(bv, off, 64);
                int   oi = __shfl_xor(bi, off, 64);
                if (ov > bv || (ov == bv && oi < bi)) { bv = ov; bi = oi; }
            }
            if (bv > -0.5f) selm |= (1ull << bi);
            if (j == bi) sc = -3e38f;
        }
        if (l == 0) sel_mask[(size_t)tqq * 2 + kv] = selm;
    }
}

// ------- Kernel 5a: slc+swa split-K, staged single-buffer K/V --------------
__global__ __launch_bounds__(64, 2) void slcswa_part_kernel(
    const short* __restrict__ qb, const short* __restrict__ krb,
    const short* __restrict__ vT, const unsigned long long* __restrict__ sel,
    short* __restrict__ slc_part, float2* __restrict__ ml_slc,
    short* __restrict__ swa_part, float2* __restrict__ ml_swa)
{
    const int t0 = (511 - blockIdx.x) * QT;     // LPT: big lists first
    const int kv = blockIdx.y;
    const int sid = blockIdx.z;                 // 0..1
    const int l  = threadIdx.x;
    const int l16 = l & 15, g4 = l >> 4;
    const int qq = l16 & 3;
    const int gg = l16 >> 2;
    __shared__ __align__(16) short kbuf[4096];
    __shared__ __align__(16) short vbuf[4096];
    __shared__ __align__(16) short plds[16][40];
    __shared__ int list_s0[48];
    __shared__ unsigned long long qm[QT];
    __shared__ int ne_s, nslc_s;

    if (l < QT) qm[l] = sel[(size_t)(t0 + l) * 2 + kv];
    __syncthreads();
    if (l == 0) {
        unsigned long long u = qm[0] | qm[1] | qm[2] | qm[3];
        int n = 0;
        while (u) { int j = __ffsll((long long)u) - 1; list_s0[n++] = j * 32; u &= u - 1; }
        nslc_s = n;
        int sLo = (t0 >= 256) ? ((t0 - 256) & ~31) : 0;
        for (int s0 = sLo; s0 <= t0 + QT - 1; s0 += 32) list_s0[n++] = s0;
        ne_s = n;
    }
    __syncthreads();
    const int nslc = nslc_s, ne = ne_s;

    const int tq = t0 + qq;
    const unsigned long long myqm = qm[qq];
    short8 qf[4];
    #pragma unroll
    for (int ks = 0; ks < 4; ++ks)
        qf[ks] = *(const short8*)(qb + ((size_t)tq * 8 + kv * 4 + gg) * 128 + ks * 32 + g4 * 8);

    #define STAGE_K(s0v)                                                          \
    {                                                                             \
        _Pragma("unroll")                                                         \
        for (int ps = 0; ps < 8; ++ps) {                                          \
            int off = ps * 1024 + (l << 4);                                       \
            int row = off >> 8, col = off & 255;                                  \
            int cs = col ^ ((row & 7) << 4);                                      \
            GLDS16(krb + (((size_t)((s0v) + row) * 2 + kv) << 7) + (cs >> 1),     \
                   &kbuf[ps * 512]);                                              \
        }                                                                         \
    }
    #define STAGE_V(s0v)                                                          \
    {                                                                             \
        _Pragma("unroll")                                                         \
        for (int ps = 0; ps < 8; ++ps) {                                          \
            int off = ps * 1024 + (l << 4);                                       \
            int row = off >> 6, col = off & 63;                                   \
            int cs = col ^ (((row >> 1) & 3) << 4);                               \
            GLDS16(vT + (size_t)(kv * 128 + row) * 2048 + (s0v) + (cs >> 1),      \
                   &vbuf[ps * 512]);                                              \
        }                                                                         \
    }

    f32x4 acc[8];
    #pragma unroll
    for (int dt = 0; dt < 8; ++dt) acc[dt] = (f32x4)0.f;
    float m_r = NEGF, l_r = 0.f;

    const size_t pbase = (size_t)(((sid * 2048 + tq) * 2 + kv) * 4 + gg) * 128;
    const int mlidx = ((sid * 2048 + tq) * 2 + kv) * 4 + gg;

    if (sid >= nslc) {
        #pragma unroll
        for (int dt = 0; dt < 8; ++dt)
            *(short4v*)(slc_part + pbase + dt * 16 + g4 * 4) = (short4v){0,0,0,0};
        if (g4 == 0) ml_slc[mlidx] = make_float2(NEGF, 0.f);
    }

    if (sid < ne) {
        STAGE_K(list_s0[sid]);
        STAGE_V(list_s0[sid]);
    }

    for (int e = sid; e < ne; e += 2) {
        const int s0 = list_s0[e];
        const int md = (e >= nslc);
        const bool has_next = (e + 2 < ne);

        asm volatile("s_waitcnt vmcnt(8)" ::: "memory");
        f32x4 sct[2];
        sct[0] = (f32x4)0.f; sct[1] = (f32x4)0.f;
        #pragma unroll
        for (int nt = 0; nt < 2; ++nt) {
            const int row = nt * 16 + l16;
            short8 kf[4];
            #pragma unroll
            for (int ks = 0; ks < 4; ++ks)
                kf[ks] = *(const short8*)&kbuf[row * 128 + ((((ks * 64 + g4 * 16) ^ ((row & 7) << 4))) >> 1)];
            #pragma unroll
            for (int ks = 0; ks < 4; ++ks)
                sct[nt] = __builtin_amdgcn_mfma_f32_16x16x32_bf16(kf[ks], qf[ks], sct[nt], 0, 0, 0);
        }
        asm volatile("s_waitcnt lgkmcnt(0)" ::: "memory");
        if (has_next) STAGE_K(list_s0[e + 2]);

        const bool inm = md ? true : ((myqm >> (s0 >> 5)) & 1ull);
        float p[8];
        float mx = NEGF;
        #pragma unroll
        for (int nt = 0; nt < 2; ++nt)
            #pragma unroll
            for (int r = 0; r < 4; ++r) {
                const int key = s0 + nt * 16 + g4 * 4 + r;
                const bool vv = md ? ((key <= tq) && (key >= tq - 256))
                                   : (inm && (key <= tq));
                const float sv = vv ? sct[nt][r] * SCALE_ : NEGF;
                p[nt * 4 + r] = sv;
                mx = fmaxf(mx, sv);
            }
        mx = fmaxf(mx, __shfl_xor(mx, 16, 64));
        mx = fmaxf(mx, __shfl_xor(mx, 32, 64));
        if (!__all(mx <= m_r + 8.0f)) {
            const float mnew = fmaxf(m_r, mx);
            const float alx = __expf(m_r - mnew);
            l_r *= alx;
            m_r = mnew;
            #pragma unroll
            for (int dt = 0; dt < 8; ++dt) acc[dt] *= alx;
        }
        float rs = 0.f;
        #pragma unroll
        for (int i = 0; i < 8; ++i) {
            float pv = (p[i] > -1e29f) ? __expf(p[i] - m_r) : 0.f;
            p[i] = pv; rs += pv;
        }
        rs += __shfl_xor(rs, 16, 64);
        rs += __shfl_xor(rs, 32, 64);
        l_r += rs;
        short4v pk0, pk1;
        #pragma unroll
        for (int r = 0; r < 4; ++r) { pk0[r] = bf16_of(p[r]); pk1[r] = bf16_of(p[4 + r]); }
        *(short4v*)&plds[l16][g4 * 4]      = pk0;
        *(short4v*)&plds[l16][16 + g4 * 4] = pk1;
        short8 pa = *(const short8*)(&plds[l16][g4 * 8]);

        if (has_next) { asm volatile("s_waitcnt vmcnt(8)" ::: "memory"); }
        else          { asm volatile("s_waitcnt vmcnt(0)" ::: "memory"); }
        #pragma unroll
        for (int dt = 0; dt < 8; ++dt) {
            const int row = dt * 16 + l16;
            short8 vf = *(const short8*)&vbuf[row * 32 + (((g4 * 16) ^ (((row >> 1) & 3) << 4)) >> 1)];
            acc[dt] = __builtin_amdgcn_mfma_f32_16x16x32_bf16(vf, pa, acc[dt], 0, 0, 0);
        }
        asm volatile("s_waitcnt lgkmcnt(0)" ::: "memory");
        if (has_next) STAGE_V(list_s0[e + 2]);

        if (!md && e + 2 >= nslc) {
            #pragma unroll
            for (int dt = 0; dt < 8; ++dt) {
                short4v pk;
                #pragma unroll
                for (int r = 0; r < 4; ++r) pk[r] = bf16_of(acc[dt][r]);
                *(short4v*)(slc_part + pbase + dt * 16 + g4 * 4) = pk;
                acc[dt] = (f32x4)0.f;
            }
            if (g4 == 0) ml_slc[mlidx] = make_float2(m_r, l_r);
            m_r = NEGF; l_r = 0.f;
        }
    }

    #pragma unroll
    for (int dt = 0; dt < 8; ++dt) {
        short4v pk;
        #pragma unroll
        for (int r = 0; r < 4; ++r) pk[r] = bf16_of(acc[dt][r]);
        *(short4v*)(swa_part + pbase + dt * 16 + g4 * 4) = pk;
    }
    if (g4 == 0) ml_swa[mlidx] = make_float2(m_r, l_r);
    #undef STAGE_K
    #undef STAGE_V
}

// ------- Kernel 5b: merge 2 splits + gated combine -------------------------
__global__ __launch_bounds__(256) void merge_kernel(
    const short* __restrict__ slc_part, const float2* __restrict__ ml_slc,
    const short* __restrict__ swa_part, const float2* __restrict__ ml_swa,
    const float* __restrict__ gsig, const float* __restrict__ o_cmp,
    float* __restrict__ out)
{
    const int t0 = blockIdx.x * 8;
    const int kv = blockIdx.y;
    for (int base = threadIdx.x * 4; base < 8 * 512; base += 256 * 4) {
        const int q_ = base >> 9, c = base & 511;
        const int gg = c >> 7, d = c & 127;
        const int tq = t0 + q_;
        const int mi0 = (tq * 2 + kv) * 4 + gg;
        const int mi1 = ((2048 + tq) * 2 + kv) * 4 + gg;
        float2 s0m = ml_slc[mi0], s1m = ml_slc[mi1];
        float M = fmaxf(s0m.x, s1m.x);
        float a0 = __expf(s0m.x - M), a1 = __expf(s1m.x - M);
        float L = s0m.y * a0 + s1m.y * a1;
        float rL = (L > 0.f) ? 1.0f / L : 0.f;
        short4v p0 = *(const short4v*)(slc_part + (size_t)mi0 * 128 + d);
        short4v p1 = *(const short4v*)(slc_part + (size_t)mi1 * 128 + d);
        float2 w0m = ml_swa[mi0], w1m = ml_swa[mi1];
        float Mw = fmaxf(w0m.x, w1m.x);
        float b0 = __expf(w0m.x - Mw), b1 = __expf(w1m.x - Mw);
        float Lw = w0m.y * b0 + w1m.y * b1;
        float rLw = (Lw > 0.f) ? 1.0f / Lw : 0.f;
        short4v q0 = *(const short4v*)(swa_part + (size_t)mi0 * 128 + d);
        short4v q1 = *(const short4v*)(swa_part + (size_t)mi1 * 128 + d);
        const float gc = gsig[(size_t)tq * 24 + kv * 12 + gg * 3 + 0];
        const float gs = gsig[(size_t)tq * 24 + kv * 12 + gg * 3 + 1];
        const float gw = gsig[(size_t)tq * 24 + kv * 12 + gg * 3 + 2];
        const size_t oi = (size_t)tq * 1024 + (kv * 4 + gg) * 128 + d;
        float4 oc = *(const float4*)(o_cmp + oi);
        float ocv[4] = {oc.x, oc.y, oc.z, oc.w};
        float res[4];
        #pragma unroll
        for (int r = 0; r < 4; ++r) {
            float oslc = (f32_of_bf16bits((unsigned short)p0[r]) * a0
                        + f32_of_bf16bits((unsigned short)p1[r]) * a1) * rL;
            float oswa = (f32_of_bf16bits((unsigned short)q0[r]) * b0
                        + f32_of_bf16bits((unsigned short)q1[r]) * b1) * rLw;
            res[r] = gc * ocv[r] + gs * oslc + gw * oswa;
        }
        float4 o4;
        o4.x = res[0]; o4.y = res[1]; o4.z = res[2]; o4.w = res[3];
        *(float4*)(out + oi) = o4;
    }
}

extern "C" void kernel_launch(void* const* d_in, const int* in_sizes, int n_in,
                              void* d_out, int out_size, void* d_ws, size_t ws_size,
                              hipStream_t stream)
{
    const float* x       = (const float*)d_in[0];
    const float* Wq      = (const float*)d_in[1];
    const float* Wk      = (const float*)d_in[2];
    const float* Wv      = (const float*)d_in[3];
    const float* Wg      = (const float*)d_in[4];
    const float* wk_pool = (const float*)d_in[5];
    const float* wv_pool = (const float*)d_in[6];
    const float* pe      = (const float*)d_in[7];
    float* out = (float*)d_out;
    float* ws  = (float*)d_ws;

    // ---- workspace layout (floats); ~45 MB ----
    float* q     = ws;                         // 2,097,152
    float* k_raw = q + 2097152;                //   524,288
    float* v     = k_raw + 524288;             //   524,288
    float* gsig  = v + 524288;                 //    49,152
    unsigned long long* sel = (unsigned long long*)(gsig + 49152); // 8,192 f
    float* o_cmp = (float*)sel + 8192;         // 2,097,152
    short* xhi   = (short*)o_cmp;              // alias o_cmp (dead before cmp writes)
    short* xlo   = xhi + 2097152;
    short* qb    = (short*)(o_cmp + 2097152);  // 2,097,152 sh
    short* krb   = qb + 2097152;               //   524,288 sh
    short* vT    = krb + 524288;               //   524,288 sh
    short* khi   = vT + 524288;                //    16,384 sh
    short* klo   = khi + 16384;                //    16,384 sh
    short* vcT   = klo + 16384;                //    16,384 sh
    short* wthi  = qb;                         // alias qb.. (dead before rope/pool)
    short* wtlo  = wthi + 1638400;             // spans krb/vT/pad
    short* qhi   = qb + 3276800;               // 2,097,152 sh (after wtlo end)
    short* qlo   = qhi + 2097152;              // 2,097,152 sh
    short* slc_part = qhi;                     // 4,194,304 sh (alias qhi+qlo)
    short* swa_part = qlo + 2097152;           // 4,194,304 sh
    float2* ml_slc  = (float2*)(swa_part + 4194304); // 32,768 float2
    float2* ml_swa  = ml_slc + 32768;                // 32,768 float2

    hipLaunchKernelGGL(prep_kernel, dim3(3648), dim3(256), 0, stream,
                       x, Wq, Wk, Wv, Wg, xhi, xlo, wthi, wtlo);
    hipLaunchKernelGGL(proj_mfma_kernel, dim3(25, 16), dim3(512), 0, stream,
                       xhi, xlo, wthi, wtlo, q, k_raw, v, gsig);
    hipLaunchKernelGGL(mid_kernel, dim3(5696), dim3(256), 0, stream,
                       q, k_raw, v, wk_pool, wv_pool, pe,
                       qb, krb, qhi, qlo, vT, khi, klo, vcT);
    hipLaunchKernelGGL(cmp_mfma_kernel, dim3(256, 2), dim3(128), 0, stream,
                       qhi, qlo, khi, klo, vcT, o_cmp, sel);
    hipLaunchKernelGGL(slcswa_part_kernel, dim3(512, 2, 2), dim3(64), 0, stream,
                       qb, krb, vT, sel, slc_part, ml_slc, swa_part, ml_swa);
    hipLaunchKernelGGL(merge_kernel, dim3(256, 2), dim3(256), 0, stream,
                       slc_part, ml_slc, swa_part, ml_swa, gsig, o_cmp, out);
}